// Round 13
// baseline (4557.546 us; speedup 1.0000x reference)
//
#include <hip/hip_runtime.h>

// LSTM fused kernel for MI355X (gfx950) — round 13: single-sync slots.
// 256 blocks x 512 threads (8 waves, 2/SIMD). Group = measured XCD; 32 batch
// rows split into tiles A/B (16 rows) alternated per slot.
// r12 transposed MFMA kept: wave (hgrp=wv&1, kh=wv>>1), z^T = W·[h|x]^T,
// lane holds all 4 gates of one (row,hcol) -> gates all-lanes, c in regs.
// NEW: (1) per-wave self-staging of own 320-K window (A-tile wave-local,
// syncA gone; pair-duplicated identical writes are benign);
// (2) zbuf double-buffered by tile -> syncC gone; flag released by the LAST
// wave via monotonic LDS ticket counter (vmcnt-drained per wave);
// (3) x pre-converted to fp16 workspace when ws_size allows (else in-stage
// cvt fallback). One __syncthreads per slot (zbuf write -> gates).
// Sync: relaxed agent flags + per-wave buffer_inv sc0 acquire, early-poll,
// deferred inv; threadfence fallback; guards 1<<18.
// Workspace: WT fp16 [4096][1280] @0, WphT @10485760,
// hbuf [2][256][1024] @11010048, lg @12058624, cnt @12320768, tick @12322816,
// xh fp16 [256][512][256] @16777216 (only if ws_size >= 83886080).

typedef _Float16 f16;
typedef _Float16 f16x8 __attribute__((ext_vector_type(8)));
typedef _Float16 f16x4 __attribute__((ext_vector_type(4)));
typedef float f32x4 __attribute__((ext_vector_type(4)));
typedef unsigned int u32;

#define WS_WT    0
#define WS_WPHT  10485760
#define WS_HBUF  11010048
#define WS_LG    12058624
#define WS_CNT   12320768
#define WS_TICK  12322816
#define WS_XH    16777216
#define WS_XH_END 83886080

// LDS: A-tile[2] [16 rows][2560B] @0/@40960 (4-bit row swizzle);
// zbuf[2 tiles][4 kh][512 x 16B] @81920 (32KB each);
// ticket counters u32[2] @147456; bcast @147464.
#define ZBT   81920u
#define CNTL  147456
#define BCAST 147464

__device__ __forceinline__ float sigm(float v) { return 1.0f / (1.0f + __expf(-v)); }
__device__ __forceinline__ float tanhfast(float v) {
  float t = __expf(-2.0f * fabsf(v));
  float r = (1.0f - t) / (1.0f + t);
  return v < 0.0f ? -r : r;
}

// ---------- prep: WT[n][k], n=gate*1024+j (z-col), k<1024 -> Wh[k][j], else Wx[k-1024][j]
__global__ __launch_bounds__(256) void prep_wt(
    const float* __restrict__ Wgh, const float* __restrict__ Wih,
    const float* __restrict__ Wfh, const float* __restrict__ Woh,
    const float* __restrict__ Wgx, const float* __restrict__ Wix,
    const float* __restrict__ Wfx, const float* __restrict__ Wox,
    f16* __restrict__ WT)
{
  __shared__ float tile[32][33];
  int bid = blockIdx.x;
  int gate = bid / 1280;
  int rem  = bid % 1280;
  int jt = rem / 40, kt = rem % 40;
  const float* srcH = (gate==0)?Wgh:(gate==1)?Wih:(gate==2)?Wfh:Woh;
  const float* srcX = (gate==0)?Wgx:(gate==1)?Wix:(gate==2)?Wfx:Wox;
  const float* src = (kt < 32) ? (srcH + (size_t)(kt*32)*1024)
                               : (srcX + (size_t)(kt*32 - 1024)*1024);
  int t = threadIdx.x;
  {
    int jl = t & 31, kg = t >> 5;
#pragma unroll
    for (int it = 0; it < 4; ++it) {
      int kl = kg + it*8;
      tile[kl][jl] = src[(size_t)kl*1024 + jt*32 + jl];
    }
  }
  __syncthreads();
  {
    int kl = t & 31, jg = t >> 5;
#pragma unroll
    for (int it = 0; it < 4; ++it) {
      int jl2 = jg + it*8;
      WT[(size_t)(gate*1024 + jt*32 + jl2)*1280 + kt*32 + kl] = (f16)tile[kl][jl2];
    }
  }
}

// ---------- prep: WphT[oc][k] = W_ph[k][oc], fp16
__global__ __launch_bounds__(256) void prep_wph(const float* __restrict__ Wph,
                                                f16* __restrict__ WphT)
{
  __shared__ float tile[32][33];
  int bid = blockIdx.x;
  int jt = bid & 7, kt = bid >> 3;
  int t = threadIdx.x;
  {
    int jl = t & 31, kg = t >> 5;
#pragma unroll
    for (int it = 0; it < 4; ++it) {
      int kl = kg + it*8;
      tile[kl][jl] = Wph[(size_t)(kt*32 + kl)*256 + jt*32 + jl];
    }
  }
  __syncthreads();
  {
    int kl = t & 31, jg = t >> 5;
#pragma unroll
    for (int it = 0; it < 4; ++it) {
      int jl2 = jg + it*8;
      WphT[(size_t)(jt*32 + jl2)*1024 + kt*32 + kl] = (f16)tile[kl][jl2];
    }
  }
}

// ---------- prep: x f32 -> f16 (33.5M elems, 16/thread)
__global__ __launch_bounds__(256) void prep_x16(const float* __restrict__ x,
                                                f16* __restrict__ xh)
{
  size_t i = ((size_t)blockIdx.x*256 + threadIdx.x) * 16;
  const float4* src = (const float4*)(x + i);
  f16x4* dst = (f16x4*)(xh + i);
#pragma unroll
  for (int j = 0; j < 4; ++j) {
    float4 v = src[j];
    f16x4 h; h[0]=(f16)v.x; h[1]=(f16)v.y; h[2]=(f16)v.z; h[3]=(f16)v.w;
    dst[j] = h;
  }
}

// ---------- main persistent LSTM kernel
__global__ __launch_bounds__(512, 2) void lstm_main(
    const float* __restrict__ x, const f16* __restrict__ xh, int use_xh,
    const f16* __restrict__ WT, const f16* __restrict__ WphT,
    f16* __restrict__ hbuf,
    const float* __restrict__ bgp, const float* __restrict__ bip,
    const float* __restrict__ bfp, const float* __restrict__ bop,
    const float* __restrict__ bpp, float* __restrict__ lg,
    u32* __restrict__ cnt, u32* __restrict__ tick, float* __restrict__ out)
{
  __shared__ __align__(16) char smem[147472];
  const int tid  = threadIdx.x;
  const int lane = tid & 63;
  const int wv   = tid >> 6;
  const int hgrp = wv & 1;         // h-col half (16 cols)
  const int kh   = wv >> 1;        // K quarter (320 elems)
  const int l15 = lane & 15, l4 = lane >> 4;

  // ---- measure XCD, take ticket on per-XCD counter
  u32 myxcd;
  asm volatile("s_getreg_b32 %0, hwreg(HW_REG_XCC_ID)" : "=s"(myxcd));
  myxcd &= 7u;
  if (tid == 0) {
    ((u32*)(smem + CNTL))[0] = 0u;   // tile-A ticket counter
    ((u32*)(smem + CNTL))[1] = 0u;   // tile-B ticket counter
    u32 t = __hip_atomic_fetch_add(tick + myxcd, 1u,
                                   __ATOMIC_RELAXED, __HIP_MEMORY_SCOPE_AGENT);
    *(volatile u32*)(smem + BCAST) = t;
  }
  if (wv == 0) {
    u32 v = 0;
    int guard = 0;
    for (;;) {
      v = (lane < 8) ? __hip_atomic_load(tick + lane, __ATOMIC_RELAXED,
                                         __HIP_MEMORY_SCOPE_AGENT) : 0u;
      u32 sum = v;
      sum += __shfl_xor(sum, 1);
      sum += __shfl_xor(sum, 2);
      sum += __shfl_xor(sum, 4);
      if (__shfl(sum, 0) == 256u) break;
      __builtin_amdgcn_s_sleep(1);
      if (++guard > (1 << 20)) break;
    }
    int even = __all((lane < 8) ? (v == 32u) : 1);
    if (lane == 0) *(volatile u32*)(smem + BCAST + 4) = (u32)even;
  }
  __syncthreads();
  const bool xloc = (*(volatile u32*)(smem + BCAST + 4)) != 0u;
  const u32 myticket = *(volatile u32*)(smem + BCAST);
  const int xg = xloc ? (int)myxcd    : (blockIdx.x & 7);   // batch-tile group
  const int cg = xloc ? (int)myticket : (blockIdx.x >> 3);  // column slice 0..31
  u32* flg = cnt + xg*64;           // [tileA flags 0..31][tileB flags 32..63]

  // ---- weight-stationary A-op fragments: [10 kk][4 frags] = 160 regs.
  // Lane l15 = m = hcolsub*4 + gate (gate-minor interleave).
  f16x8 Breg[10][4];
  {
    const int gate = l15 & 3, hsub = l15 >> 2;
#pragma unroll
    for (int f = 0; f < 4; ++f) {
      const int n = gate*1024 + cg*32 + hgrp*16 + f*4 + hsub;
      const f16* wb = WT + (size_t)n*1280 + kh*320 + l4*8;
#pragma unroll
      for (int kk = 0; kk < 10; ++kk) {
        Breg[kk][f] = *(const f16x8*)(wb + kk*32);
        asm volatile("" : "+v"(Breg[kk][f]));   // pin: no remat
      }
    }
  }

  // per-thread bias (gates phase handles hcol = tid&31)
  const int bcol = cg*32 + (tid & 31);
  const float bgr = bgp[bcol], bir = bip[bcol], bfr = bfp[bcol], bor = bop[bcol];

  // B-op (activations) frag addressing: lane l15 = batch row
  const u32 aoff = (u32)l15*2560u + (u32)(kh*640 + l4*16);
  const u32 aswz = (u32)l15 << 4;
  // per-wave staging: lane -> row r16 = lane&15, chunk group c4 = lane>>4
  const int r16 = lane & 15;
  const int c4  = lane >> 4;
  const u32 sswz = (u32)r16 << 4;

  // c state in registers (gates thread owns (row=tid>>5, hcol=tid&31))
  float cA = 0.0f, cB = 0.0f;

  u32 pre = 0xFFFFFFFFu;
  bool preOK = false;

#pragma unroll 1
  for (int slot = 0; slot < 1024; ++slot) {
    const int T = slot & 1, s = slot >> 1;
    const u32 Abase = (u32)T * 40960u;
    const u32 Zt = ZBT + (u32)T * 32768u;
    u32* flgT = flg + T*32;
    const int gT = xg*32 + T*16 + r16;       // staging batch row

    // ---- x stage (kh==3 pair only, own region, wave-local) — pre-barrier
    if (kh == 3) {
      if (use_xh) {
        const char* xrow = (const char*)xh + ((size_t)gT*512 + (size_t)s)*512;
#pragma unroll
        for (int j = 0; j < 10; ++j) {
          int cc = c4 + 4*j;
          if (cc >= 8) {
            uint4 v = *(const uint4*)(xrow + (cc - 8)*16);
            *(uint4*)(smem + Abase + (((u32)r16*2560u + (u32)(1920 + cc*16)) ^ sswz)) = v;
          }
        }
      } else {
        const float* xrowf = x + ((size_t)gT*512 + (size_t)s)*256;
#pragma unroll
        for (int j = 0; j < 10; ++j) {
          int cc = c4 + 4*j;
          if (cc >= 8) {
            const float* p = xrowf + (cc - 8)*8;
            float4 a = *(const float4*)p, b = *(const float4*)(p + 4);
            f16x8 hv;
            hv[0]=(f16)a.x; hv[1]=(f16)a.y; hv[2]=(f16)a.z; hv[3]=(f16)a.w;
            hv[4]=(f16)b.x; hv[5]=(f16)b.y; hv[6]=(f16)b.z; hv[7]=(f16)b.w;
            *(f16x8*)(smem + Abase + (((u32)r16*2560u + (u32)(1920 + cc*16)) ^ sswz)) = hv;
          }
        }
      }
    }
    // ---- per-wave barrier: only if this wave's early-poll didn't confirm
    if (s > 0 && !preOK) {
      const u32 tgt = (u32)s;
      u32 v = tgt;
      int guard = 0;
      for (;;) {
        if (lane < 32)
          v = __hip_atomic_load(flgT + lane, __ATOMIC_RELAXED,
                                __HIP_MEMORY_SCOPE_AGENT);
        if (__all(v >= tgt)) break;
        __builtin_amdgcn_s_sleep(1);
        if (++guard > (1 << 18)) break;
      }
      if (lane == 0) {
        if (xloc) { asm volatile("buffer_inv sc0\n\ts_waitcnt vmcnt(0)" ::: "memory"); }
        else      { __threadfence(); }
      }
    }
    // ---- per-wave h stage: own K-window (kh<3: 10 chunks; kh==3: 2 chunks)
    {
      const char* hrow = (const char*)hbuf + (size_t)(s & 1)*524288
                       + (size_t)gT*2048;
#pragma unroll
      for (int j = 0; j < 10; ++j) {
        int cc = c4 + 4*j;
        if (!(kh == 3 && cc >= 8)) {
          uint4 v = *(const uint4*)(hrow + kh*640 + cc*16);
          *(uint4*)(smem + Abase + (((u32)r16*2560u + (u32)(kh*640 + cc*16)) ^ sswz)) = v;
        }
      }
    }
    // fence: staging ds_writes complete before this wave's ds_reads
    asm volatile("s_waitcnt lgkmcnt(0)" ::: "memory");
    __builtin_amdgcn_sched_barrier(0);
    // ---- K loop: K/4 per wave; one av feeds 4 gate-frags
    f32x4 acc0 = {}, acc1 = {}, acc2 = {}, acc3 = {};
#pragma unroll
    for (int kk = 0; kk < 10; ++kk) {
      f16x8 av = *(const f16x8*)(smem + Abase + ((aoff + (u32)kk*64u) ^ aswz));
      acc0 = __builtin_amdgcn_mfma_f32_16x16x32_f16(Breg[kk][0], av, acc0, 0, 0, 0);
      acc1 = __builtin_amdgcn_mfma_f32_16x16x32_f16(Breg[kk][1], av, acc1, 0, 0, 0);
      acc2 = __builtin_amdgcn_mfma_f32_16x16x32_f16(Breg[kk][2], av, acc2, 0, 0, 0);
      acc3 = __builtin_amdgcn_mfma_f32_16x16x32_f16(Breg[kk][3], av, acc3, 0, 0, 0);
    }
    // ---- early poll (all waves): next slot's flags, consumed after gates
    {
      const int nT = (slot + 1) & 1, nS = (slot + 1) >> 1;
      pre = 0xFFFFFFFFu;
      if (nS > 0 && nS < 512 && lane < 32)
        pre = __hip_atomic_load(flg + nT*32 + lane, __ATOMIC_RELAXED,
                                __HIP_MEMORY_SCOPE_AGENT);
    }
    // ---- zbuf[T] partial write: f32x4 at slot16 = (row*32+hcol) ^ (row&7)
    {
      const u32 zkh = Zt + (u32)kh*8192u;
#pragma unroll
      for (int f = 0; f < 4; ++f) {
        const u32 hcol = (u32)(hgrp*16 + f*4 + l4);
        const u32 s16 = ((u32)(l15*32) + hcol) ^ ((u32)(l15 & 7));
        f32x4 acc = (f==0)?acc0:(f==1)?acc1:(f==2)?acc2:acc3;
        *(f32x4*)(smem + zkh + s16*16u) = acc;
      }
    }
    __syncthreads();   // THE slot barrier: zbuf[T] ready; guards t+2 reuse
    // ---- gates: thread (row=tid>>5, hcol=tid&31), all lanes active
    {
      f16* hw = hbuf + (size_t)((s & 1) ^ 1)*262144;
      const int row = tid >> 5, hcol = tid & 31;
      const u32 s16 = ((u32)(row*32) + (u32)hcol) ^ ((u32)(row & 7));
      const u32 ro = s16*16u;
      f32x4 z0 = *(const f32x4*)(smem + Zt +          ro);
      f32x4 z1 = *(const f32x4*)(smem + Zt + 8192u  + ro);
      f32x4 z2 = *(const f32x4*)(smem + Zt + 16384u + ro);
      f32x4 z3 = *(const f32x4*)(smem + Zt + 24576u + ro);
      float zg = z0[0] + z1[0] + z2[0] + z3[0] + bgr;
      float zi = z0[1] + z1[1] + z2[1] + z3[1] + bir;
      float zf = z0[2] + z1[2] + z2[2] + z3[2] + bfr;
      float zo = z0[3] + z1[3] + z2[3] + z3[3] + bor;
      float cv = T ? cB : cA;
      float gv = tanhfast(zg);
      float iv = sigm(zi);
      float fv = sigm(zf);
      float ov = sigm(zo);
      float cn = gv*iv + cv*fv;
      if (T) cB = cn; else cA = cn;
      hw[(size_t)(xg*32 + T*16 + row)*1024 + cg*32 + hcol] = (f16)(tanhfast(cn) * ov);
    }
    // ---- flag release: last wave (monotonic LDS ticket) stores group flag
    asm volatile("s_waitcnt vmcnt(0)" ::: "memory");   // wave's h-stores in L2
    if (lane == 0) {
      u32 old = atomicAdd((u32*)(smem + CNTL) + T, 1u);
      if (old == (u32)(8*s + 7)) {
        if (!xloc) __threadfence();
        __hip_atomic_store(flgT + cg, (u32)(s + 1),
                           __ATOMIC_RELAXED, __HIP_MEMORY_SCOPE_AGENT);
      }
    }
    // ---- preOK eval + deferred inv (per wave)
    {
      const int nS = (slot + 1) >> 1;
      bool ok = (nS >= 512) || __all(pre >= (u32)nS);
      preOK = xloc && ok;
      if (preOK && nS < 512 && lane == 0) {
        asm volatile("buffer_inv sc0\n\ts_waitcnt vmcnt(0)" ::: "memory");
      }
    }
  }

  // ---- epilogue: wait both tiles at 512, logits = h @ WphT + bp
  if (wv == 0) {
    u32 v = 512u;
    int guard = 0;
    for (;;) {
      v = __hip_atomic_load(flg + lane, __ATOMIC_RELAXED,
                            __HIP_MEMORY_SCOPE_AGENT);   // lanes 0-63 = A,B
      if (__all(v >= 512u)) break;
      __builtin_amdgcn_s_sleep(1);
      if (++guard > (1 << 18)) break;
    }
    if (lane == 0) {
      if (xloc) { asm volatile("buffer_inv sc0\n\ts_waitcnt vmcnt(0)" ::: "memory"); }
      else      { __threadfence(); }
    }
  }
  __syncthreads();
  {
#pragma unroll 1
    for (int p = 0; p < 32; ++p) {
      int rowl = wv*4 + (p >> 3);
      int oc   = p & 7;
      const f16* hp = hbuf + (size_t)(xg*32 + rowl)*1024 + lane*16;  // buf 0 = h_T
      const f16* wp = WphT + (size_t)(cg*8 + oc)*1024 + lane*16;
      f16x8 h0 = *(const f16x8*)hp;
      f16x8 h1 = *(const f16x8*)(hp + 8);
      f16x8 w0 = *(const f16x8*)wp;
      f16x8 w1 = *(const f16x8*)(wp + 8);
      float sum = 0.f;
#pragma unroll
      for (int q = 0; q < 8; ++q)
        sum += (float)h0[q]*(float)w0[q] + (float)h1[q]*(float)w1[q];
#pragma unroll
      for (int d = 1; d < 64; d <<= 1) sum += __shfl_xor(sum, d);
      if (lane == 0)
        lg[(size_t)(xg*32 + rowl)*256 + cg*8 + oc] = sum + bpp[cg*8 + oc];
    }
  }
  __syncthreads();   // drain lg stores
  if (tid == 0) {
    if (!xloc) __threadfence();
    __hip_atomic_store(flg + cg, 513u, __ATOMIC_RELAXED, __HIP_MEMORY_SCOPE_AGENT);
  }
  if (wv == 0) {
    u32 v = 513u;
    int guard = 0;
    for (;;) {
      if (lane < 32)
        v = __hip_atomic_load(flg + lane, __ATOMIC_RELAXED, __HIP_MEMORY_SCOPE_AGENT);
      if (__all(v >= 513u)) break;
      __builtin_amdgcn_s_sleep(1);
      if (++guard > (1 << 18)) break;
    }
    if (lane == 0) {
      if (xloc) { asm volatile("buffer_inv sc0\n\ts_waitcnt vmcnt(0)" ::: "memory"); }
      else      { __threadfence(); }
    }
  }
  __syncthreads();
  // ---- softmax: this block handles row xg*32+cg, wave 0 only
  if (tid < 64) {
    int rowg = xg*32 + cg;
    const float* lr = lg + (size_t)rowg*256;
    float v0 = lr[tid], v1 = lr[tid+64], v2 = lr[tid+128], v3 = lr[tid+192];
    float mx = fmaxf(fmaxf(v0, v1), fmaxf(v2, v3));
#pragma unroll
    for (int d = 1; d < 64; d <<= 1) mx = fmaxf(mx, __shfl_xor(mx, d));
    float e0 = __expf(v0-mx), e1 = __expf(v1-mx), e2 = __expf(v2-mx), e3 = __expf(v3-mx);
    float sm = e0+e1+e2+e3;
#pragma unroll
    for (int d = 1; d < 64; d <<= 1) sm += __shfl_xor(sm, d);
    float inv = 1.0f / sm;
    float* orow = out + (size_t)rowg*256;
    orow[tid]      = e0*inv;
    orow[tid+64]   = e1*inv;
    orow[tid+128]  = e2*inv;
    orow[tid+192]  = e3*inv;
  }
}

extern "C" void kernel_launch(void* const* d_in, const int* in_sizes, int n_in,
                              void* d_out, int out_size, void* d_ws, size_t ws_size,
                              hipStream_t stream) {
  (void)in_sizes; (void)n_in; (void)out_size;
  const float* x   = (const float*)d_in[0];
  const float* Wgx = (const float*)d_in[1];
  const float* Wgh = (const float*)d_in[2];
  const float* bg  = (const float*)d_in[3];
  const float* Wix = (const float*)d_in[4];
  const float* Wih = (const float*)d_in[5];
  const float* bi  = (const float*)d_in[6];
  const float* Wfx = (const float*)d_in[7];
  const float* Wfh = (const float*)d_in[8];
  const float* bf  = (const float*)d_in[9];
  const float* Wox = (const float*)d_in[10];
  const float* Woh = (const float*)d_in[11];
  const float* bo  = (const float*)d_in[12];
  const float* Wph = (const float*)d_in[13];
  const float* bp  = (const float*)d_in[14];

  char* ws = (char*)d_ws;
  f16*   WT   = (f16*)(ws + WS_WT);
  f16*   WphT = (f16*)(ws + WS_WPHT);
  f16*   hbuf = (f16*)(ws + WS_HBUF);
  float* lg   = (float*)(ws + WS_LG);
  u32*   cnt  = (u32*)(ws + WS_CNT);
  u32*   tick = (u32*)(ws + WS_TICK);
  const int use_xh = (ws_size >= (size_t)WS_XH_END) ? 1 : 0;
  f16*   xh   = (f16*)(ws + WS_XH);

  // h0 = 0 (buffer 0); flags + tickets = 0 (replay-safe)
  hipMemsetAsync(hbuf, 0, 524288, stream);
  hipMemsetAsync(cnt, 0, 2048 + 64, stream);

  prep_wt<<<5120, 256, 0, stream>>>(Wgh, Wih, Wfh, Woh, Wgx, Wix, Wfx, Wox, WT);
  prep_wph<<<256, 256, 0, stream>>>(Wph, WphT);
  if (use_xh)
    prep_x16<<<8192, 256, 0, stream>>>(x, xh);
  lstm_main<<<256, 512, 0, stream>>>(x, xh, use_xh, WT, WphT, hbuf,
                                     bg, bi, bf, bo, bp,
                                     lg, cnt, tick, (float*)d_out);
}

// Round 14
// 2602.997 us; speedup vs baseline: 1.7509x; 1.7509x over previous
//
#include <hip/hip_runtime.h>

// LSTM fused kernel for MI355X (gfx950) — round 14: r12 base + the two good
// r13 pieces (xh fp16 precompute; zbuf dbuf + LDS-ticket flag release), with
// r12's COOPERATIVE staging restored (r13's per-wave staging exposed L2
// latency: MfmaUtil/VALUBusy both fell — barrier-aggregated staging wins).
// 256 blocks x 512 threads (8 waves, 2/SIMD). Group = measured XCD; 32 batch
// rows split into tiles A/B (16 rows) alternated per slot.
// Transposed MFMA: wave (hgrp=wv&1, kh=wv>>1), z^T = W·[h|x]^T, lane holds
// all 4 gates of one (row,hcol); cross-kh reduce via dbuf zbuf; c in regs.
// 2 syncthreads/slot: (A) staging->K-loop, (B) zbuf->gates. Slot end is
// barrier-free: per-wave vmcnt drain + LDS ticket; 8th wave posts group flag.
// Sync: relaxed agent flags + per-wave buffer_inv sc0 acquire, early-poll,
// deferred inv; threadfence fallback; guards 1<<18.
// Workspace: WT fp16 [4096][1280] @0, WphT @10485760,
// hbuf [2][256][1024] @11010048, lg @12058624, cnt @12320768, tick @12322816,
// xh fp16 [256][512][256] @16777216 (only if ws_size >= 83886080).

typedef _Float16 f16;
typedef _Float16 f16x8 __attribute__((ext_vector_type(8)));
typedef _Float16 f16x4 __attribute__((ext_vector_type(4)));
typedef float f32x4 __attribute__((ext_vector_type(4)));
typedef unsigned int u32;

#define WS_WT    0
#define WS_WPHT  10485760
#define WS_HBUF  11010048
#define WS_LG    12058624
#define WS_CNT   12320768
#define WS_TICK  12322816
#define WS_XH    16777216
#define WS_XH_END 83886080

// LDS: A-tile[2] [16 rows][2560B] @0/@40960 (4-bit row swizzle);
// zbuf[2 tiles][4 kh][512 x 16B] @81920 (32KB each);
// ticket counters u32[2] @147456; bcast @147464.
#define ZBT   81920u
#define CNTL  147456
#define BCAST 147464

__device__ __forceinline__ float sigm(float v) { return 1.0f / (1.0f + __expf(-v)); }
__device__ __forceinline__ float tanhfast(float v) {
  float t = __expf(-2.0f * fabsf(v));
  float r = (1.0f - t) / (1.0f + t);
  return v < 0.0f ? -r : r;
}

// ---------- prep: WT[n][k], n=gate*1024+j (z-col), k<1024 -> Wh[k][j], else Wx[k-1024][j]
__global__ __launch_bounds__(256) void prep_wt(
    const float* __restrict__ Wgh, const float* __restrict__ Wih,
    const float* __restrict__ Wfh, const float* __restrict__ Woh,
    const float* __restrict__ Wgx, const float* __restrict__ Wix,
    const float* __restrict__ Wfx, const float* __restrict__ Wox,
    f16* __restrict__ WT)
{
  __shared__ float tile[32][33];
  int bid = blockIdx.x;
  int gate = bid / 1280;
  int rem  = bid % 1280;
  int jt = rem / 40, kt = rem % 40;
  const float* srcH = (gate==0)?Wgh:(gate==1)?Wih:(gate==2)?Wfh:Woh;
  const float* srcX = (gate==0)?Wgx:(gate==1)?Wix:(gate==2)?Wfx:Wox;
  const float* src = (kt < 32) ? (srcH + (size_t)(kt*32)*1024)
                               : (srcX + (size_t)(kt*32 - 1024)*1024);
  int t = threadIdx.x;
  {
    int jl = t & 31, kg = t >> 5;
#pragma unroll
    for (int it = 0; it < 4; ++it) {
      int kl = kg + it*8;
      tile[kl][jl] = src[(size_t)kl*1024 + jt*32 + jl];
    }
  }
  __syncthreads();
  {
    int kl = t & 31, jg = t >> 5;
#pragma unroll
    for (int it = 0; it < 4; ++it) {
      int jl2 = jg + it*8;
      WT[(size_t)(gate*1024 + jt*32 + jl2)*1280 + kt*32 + kl] = (f16)tile[kl][jl2];
    }
  }
}

// ---------- prep: WphT[oc][k] = W_ph[k][oc], fp16
__global__ __launch_bounds__(256) void prep_wph(const float* __restrict__ Wph,
                                                f16* __restrict__ WphT)
{
  __shared__ float tile[32][33];
  int bid = blockIdx.x;
  int jt = bid & 7, kt = bid >> 3;
  int t = threadIdx.x;
  {
    int jl = t & 31, kg = t >> 5;
#pragma unroll
    for (int it = 0; it < 4; ++it) {
      int kl = kg + it*8;
      tile[kl][jl] = Wph[(size_t)(kt*32 + kl)*256 + jt*32 + jl];
    }
  }
  __syncthreads();
  {
    int kl = t & 31, jg = t >> 5;
#pragma unroll
    for (int it = 0; it < 4; ++it) {
      int jl2 = jg + it*8;
      WphT[(size_t)(jt*32 + jl2)*1024 + kt*32 + kl] = (f16)tile[kl][jl2];
    }
  }
}

// ---------- prep: x f32 -> f16 (33.5M elems, 16/thread)
__global__ __launch_bounds__(256) void prep_x16(const float* __restrict__ x,
                                                f16* __restrict__ xh)
{
  size_t i = ((size_t)blockIdx.x*256 + threadIdx.x) * 16;
  const float4* src = (const float4*)(x + i);
  f16x4* dst = (f16x4*)(xh + i);
#pragma unroll
  for (int j = 0; j < 4; ++j) {
    float4 v = src[j];
    f16x4 h; h[0]=(f16)v.x; h[1]=(f16)v.y; h[2]=(f16)v.z; h[3]=(f16)v.w;
    dst[j] = h;
  }
}

// ---------- main persistent LSTM kernel
__global__ __launch_bounds__(512, 2) void lstm_main(
    const float* __restrict__ x, const f16* __restrict__ xh, int use_xh,
    const f16* __restrict__ WT, const f16* __restrict__ WphT,
    f16* __restrict__ hbuf,
    const float* __restrict__ bgp, const float* __restrict__ bip,
    const float* __restrict__ bfp, const float* __restrict__ bop,
    const float* __restrict__ bpp, float* __restrict__ lg,
    u32* __restrict__ cnt, u32* __restrict__ tick, float* __restrict__ out)
{
  __shared__ __align__(16) char smem[147472];
  const int tid  = threadIdx.x;
  const int lane = tid & 63;
  const int wv   = tid >> 6;
  const int hgrp = wv & 1;         // h-col half (16 cols)
  const int kh   = wv >> 1;        // K quarter (320 elems)
  const int l15 = lane & 15, l4 = lane >> 4;

  // ---- measure XCD, take ticket on per-XCD counter
  u32 myxcd;
  asm volatile("s_getreg_b32 %0, hwreg(HW_REG_XCC_ID)" : "=s"(myxcd));
  myxcd &= 7u;
  if (tid == 0) {
    ((u32*)(smem + CNTL))[0] = 0u;   // tile-A ticket counter
    ((u32*)(smem + CNTL))[1] = 0u;   // tile-B ticket counter
    u32 t = __hip_atomic_fetch_add(tick + myxcd, 1u,
                                   __ATOMIC_RELAXED, __HIP_MEMORY_SCOPE_AGENT);
    *(volatile u32*)(smem + BCAST) = t;
  }
  if (wv == 0) {
    u32 v = 0;
    int guard = 0;
    for (;;) {
      v = (lane < 8) ? __hip_atomic_load(tick + lane, __ATOMIC_RELAXED,
                                         __HIP_MEMORY_SCOPE_AGENT) : 0u;
      u32 sum = v;
      sum += __shfl_xor(sum, 1);
      sum += __shfl_xor(sum, 2);
      sum += __shfl_xor(sum, 4);
      if (__shfl(sum, 0) == 256u) break;
      __builtin_amdgcn_s_sleep(1);
      if (++guard > (1 << 20)) break;
    }
    int even = __all((lane < 8) ? (v == 32u) : 1);
    if (lane == 0) *(volatile u32*)(smem + BCAST + 4) = (u32)even;
  }
  __syncthreads();
  const bool xloc = (*(volatile u32*)(smem + BCAST + 4)) != 0u;
  const u32 myticket = *(volatile u32*)(smem + BCAST);
  const int xg = xloc ? (int)myxcd    : (blockIdx.x & 7);   // batch-tile group
  const int cg = xloc ? (int)myticket : (blockIdx.x >> 3);  // column slice 0..31
  u32* flg = cnt + xg*64;           // [tileA flags 0..31][tileB flags 32..63]

  // ---- weight-stationary A-op fragments: [10 kk][4 frags] = 160 regs.
  // Lane l15 = m = hcolsub*4 + gate (gate-minor interleave).
  f16x8 Breg[10][4];
  {
    const int gate = l15 & 3, hsub = l15 >> 2;
#pragma unroll
    for (int f = 0; f < 4; ++f) {
      const int n = gate*1024 + cg*32 + hgrp*16 + f*4 + hsub;
      const f16* wb = WT + (size_t)n*1280 + kh*320 + l4*8;
#pragma unroll
      for (int kk = 0; kk < 10; ++kk) {
        Breg[kk][f] = *(const f16x8*)(wb + kk*32);
        asm volatile("" : "+v"(Breg[kk][f]));   // pin: no remat
      }
    }
  }

  // per-thread bias (gates phase handles hcol = tid&31)
  const int bcol = cg*32 + (tid & 31);
  const float bgr = bgp[bcol], bir = bip[bcol], bfr = bfp[bcol], bor = bop[bcol];

  // B-op (activations) frag addressing: lane l15 = batch row
  const u32 aoff = (u32)l15*2560u + (u32)(kh*640 + l4*16);
  const u32 aswz = (u32)l15 << 4;
  // cooperative staging: 16 rows x 32 segs (512 threads), 4-bit swizzle
  const int srow = tid >> 5;       // 0..15
  const int sseg = tid & 31;       // 0..31
  const u32 swzr = (u32)srow << 4;

  // c state in registers (gates thread owns (row=tid>>5, hcol=tid&31))
  float cA = 0.0f, cB = 0.0f;

  u32 pre = 0xFFFFFFFFu;
  bool preOK = false;

#pragma unroll 1
  for (int slot = 0; slot < 1024; ++slot) {
    const int T = slot & 1, s = slot >> 1;
    const u32 Abase = (u32)T * 40960u;
    const u32 Zt = ZBT + (u32)T * 32768u;
    u32* flgT = flg + T*32;
    const int grow = xg*32 + T*16 + srow;

    // ---- x stage (pre-spin; A-tile[T] last read at K-loop(slot-2), all
    // waves past syncA(slot-1) -> safe). Overlaps flag latency.
    if (use_xh) {
      const char* xrow = (const char*)xh + ((size_t)grow*512 + (size_t)s)*512;
      uint4 v = *(const uint4*)(xrow + sseg*16);
      *(uint4*)(smem + Abase + (((u32)srow*2560u + 2048u + (u32)sseg*16u) ^ swzr)) = v;
    } else {
      const float* xsrc = x + ((size_t)grow*512 + (size_t)s)*256;
      float4 xv0 = *(const float4*)(xsrc + (sseg*8)    );
      float4 xv1 = *(const float4*)(xsrc + (sseg*8) + 4);
      f16x8 hv;
      hv[0]=(f16)xv0.x; hv[1]=(f16)xv0.y; hv[2]=(f16)xv0.z; hv[3]=(f16)xv0.w;
      hv[4]=(f16)xv1.x; hv[5]=(f16)xv1.y; hv[6]=(f16)xv1.z; hv[7]=(f16)xv1.w;
      *(f16x8*)(smem + Abase + (((u32)srow*2560u + 2048u + (u32)sseg*16u) ^ swzr)) = hv;
    }
    // ---- per-wave barrier: only if this wave's early-poll didn't confirm
    if (s > 0 && !preOK) {
      const u32 tgt = (u32)s;
      u32 v = tgt;
      int guard = 0;
      for (;;) {
        if (lane < 32)
          v = __hip_atomic_load(flgT + lane, __ATOMIC_RELAXED,
                                __HIP_MEMORY_SCOPE_AGENT);
        if (__all(v >= tgt)) break;
        __builtin_amdgcn_s_sleep(1);
        if (++guard > (1 << 18)) break;
      }
      if (lane == 0) {
        if (xloc) { asm volatile("buffer_inv sc0\n\ts_waitcnt vmcnt(0)" ::: "memory"); }
        else      { __threadfence(); }
      }
    }
    // ---- cooperative h stage [16 rows x 1024] fp16, XOR-swizzled (4-bit)
    {
      const f16* hsrc = hbuf + (size_t)(s & 1)*262144 + (size_t)grow*1024;
#pragma unroll
      for (int j = 0; j < 4; ++j) {
        int chunk = sseg + 32*j;                       // 16B chunk of h row
        uint4 v = *(const uint4*)(hsrc + chunk*8);
        *(uint4*)(smem + Abase + (((u32)srow*2560u + 16u*(u32)chunk) ^ swzr)) = v;
      }
    }
    __syncthreads();   // (A) staging complete; also orders slot-2 reuse
    // ---- K loop: K/4 per wave; one av feeds 4 gate-frags
    f32x4 acc0 = {}, acc1 = {}, acc2 = {}, acc3 = {};
#pragma unroll
    for (int kk = 0; kk < 10; ++kk) {
      f16x8 av = *(const f16x8*)(smem + Abase + ((aoff + (u32)kk*64u) ^ aswz));
      acc0 = __builtin_amdgcn_mfma_f32_16x16x32_f16(Breg[kk][0], av, acc0, 0, 0, 0);
      acc1 = __builtin_amdgcn_mfma_f32_16x16x32_f16(Breg[kk][1], av, acc1, 0, 0, 0);
      acc2 = __builtin_amdgcn_mfma_f32_16x16x32_f16(Breg[kk][2], av, acc2, 0, 0, 0);
      acc3 = __builtin_amdgcn_mfma_f32_16x16x32_f16(Breg[kk][3], av, acc3, 0, 0, 0);
    }
    // ---- early poll (all waves): next slot's flags, consumed after gates
    {
      const int nT = (slot + 1) & 1, nS = (slot + 1) >> 1;
      pre = 0xFFFFFFFFu;
      if (nS > 0 && nS < 512 && lane < 32)
        pre = __hip_atomic_load(flg + nT*32 + lane, __ATOMIC_RELAXED,
                                __HIP_MEMORY_SCOPE_AGENT);
    }
    // ---- zbuf[T] partial write: f32x4 at slot16 = (row*32+hcol) ^ (row&7)
    {
      const u32 zkh = Zt + (u32)kh*8192u;
#pragma unroll
      for (int f = 0; f < 4; ++f) {
        const u32 hcol = (u32)(hgrp*16 + f*4 + l4);
        const u32 s16 = ((u32)(l15*32) + hcol) ^ ((u32)(l15 & 7));
        f32x4 acc = (f==0)?acc0:(f==1)?acc1:(f==2)?acc2:acc3;
        *(f32x4*)(smem + zkh + s16*16u) = acc;
      }
    }
    __syncthreads();   // (B) zbuf[T] ready
    // ---- gates: thread (row=tid>>5, hcol=tid&31), all lanes active
    {
      f16* hw = hbuf + (size_t)((s & 1) ^ 1)*262144;
      const int row = tid >> 5, hcol = tid & 31;
      const u32 s16 = ((u32)(row*32) + (u32)hcol) ^ ((u32)(row & 7));
      const u32 ro = s16*16u;
      f32x4 z0 = *(const f32x4*)(smem + Zt +          ro);
      f32x4 z1 = *(const f32x4*)(smem + Zt + 8192u  + ro);
      f32x4 z2 = *(const f32x4*)(smem + Zt + 16384u + ro);
      f32x4 z3 = *(const f32x4*)(smem + Zt + 24576u + ro);
      float zg = z0[0] + z1[0] + z2[0] + z3[0] + bgr;
      float zi = z0[1] + z1[1] + z2[1] + z3[1] + bir;
      float zf = z0[2] + z1[2] + z2[2] + z3[2] + bfr;
      float zo = z0[3] + z1[3] + z2[3] + z3[3] + bor;
      float cv = T ? cB : cA;
      float gv = tanhfast(zg);
      float iv = sigm(zi);
      float fv = sigm(zf);
      float ov = sigm(zo);
      float cn = gv*iv + cv*fv;
      if (T) cB = cn; else cA = cn;
      hw[(size_t)(xg*32 + T*16 + row)*1024 + cg*32 + hcol] = (f16)(tanhfast(cn) * ov);
    }
    // ---- slot end (barrier-free): per-wave vmcnt drain + LDS ticket;
    // 8th wave of this tile posts the group flag.
    asm volatile("s_waitcnt vmcnt(0)" ::: "memory");   // wave's h-stores in L2
    if (lane == 0) {
      u32 old = atomicAdd((u32*)(smem + CNTL) + T, 1u);
      if (old == (u32)(8*s + 7)) {
        if (!xloc) __threadfence();
        __hip_atomic_store(flgT + cg, (u32)(s + 1),
                           __ATOMIC_RELAXED, __HIP_MEMORY_SCOPE_AGENT);
      }
    }
    // ---- preOK eval + deferred inv (per wave)
    {
      const int nS = (slot + 1) >> 1;
      bool ok = (nS >= 512) || __all(pre >= (u32)nS);
      preOK = xloc && ok;
      if (preOK && nS < 512 && lane == 0) {
        asm volatile("buffer_inv sc0\n\ts_waitcnt vmcnt(0)" ::: "memory");
      }
    }
  }

  // ---- epilogue: wait both tiles at 512, logits = h @ WphT + bp
  if (wv == 0) {
    u32 v = 512u;
    int guard = 0;
    for (;;) {
      v = __hip_atomic_load(flg + lane, __ATOMIC_RELAXED,
                            __HIP_MEMORY_SCOPE_AGENT);   // lanes 0-63 = A,B
      if (__all(v >= 512u)) break;
      __builtin_amdgcn_s_sleep(1);
      if (++guard > (1 << 18)) break;
    }
    if (lane == 0) {
      if (xloc) { asm volatile("buffer_inv sc0\n\ts_waitcnt vmcnt(0)" ::: "memory"); }
      else      { __threadfence(); }
    }
  }
  __syncthreads();
  {
#pragma unroll 1
    for (int p = 0; p < 32; ++p) {
      int rowl = wv*4 + (p >> 3);
      int oc   = p & 7;
      const f16* hp = hbuf + (size_t)(xg*32 + rowl)*1024 + lane*16;  // buf 0 = h_T
      const f16* wp = WphT + (size_t)(cg*8 + oc)*1024 + lane*16;
      f16x8 h0 = *(const f16x8*)hp;
      f16x8 h1 = *(const f16x8*)(hp + 8);
      f16x8 w0 = *(const f16x8*)wp;
      f16x8 w1 = *(const f16x8*)(wp + 8);
      float sum = 0.f;
#pragma unroll
      for (int q = 0; q < 8; ++q)
        sum += (float)h0[q]*(float)w0[q] + (float)h1[q]*(float)w1[q];
#pragma unroll
      for (int d = 1; d < 64; d <<= 1) sum += __shfl_xor(sum, d);
      if (lane == 0)
        lg[(size_t)(xg*32 + rowl)*256 + cg*8 + oc] = sum + bpp[cg*8 + oc];
    }
  }
  __syncthreads();   // drain lg stores
  if (tid == 0) {
    if (!xloc) __threadfence();
    __hip_atomic_store(flg + cg, 513u, __ATOMIC_RELAXED, __HIP_MEMORY_SCOPE_AGENT);
  }
  if (wv == 0) {
    u32 v = 513u;
    int guard = 0;
    for (;;) {
      if (lane < 32)
        v = __hip_atomic_load(flg + lane, __ATOMIC_RELAXED, __HIP_MEMORY_SCOPE_AGENT);
      if (__all(v >= 513u)) break;
      __builtin_amdgcn_s_sleep(1);
      if (++guard > (1 << 18)) break;
    }
    if (lane == 0) {
      if (xloc) { asm volatile("buffer_inv sc0\n\ts_waitcnt vmcnt(0)" ::: "memory"); }
      else      { __threadfence(); }
    }
  }
  __syncthreads();
  // ---- softmax: this block handles row xg*32+cg, wave 0 only
  if (tid < 64) {
    int rowg = xg*32 + cg;
    const float* lr = lg + (size_t)rowg*256;
    float v0 = lr[tid], v1 = lr[tid+64], v2 = lr[tid+128], v3 = lr[tid+192];
    float mx = fmaxf(fmaxf(v0, v1), fmaxf(v2, v3));
#pragma unroll
    for (int d = 1; d < 64; d <<= 1) mx = fmaxf(mx, __shfl_xor(mx, d));
    float e0 = __expf(v0-mx), e1 = __expf(v1-mx), e2 = __expf(v2-mx), e3 = __expf(v3-mx);
    float sm = e0+e1+e2+e3;
#pragma unroll
    for (int d = 1; d < 64; d <<= 1) sm += __shfl_xor(sm, d);
    float inv = 1.0f / sm;
    float* orow = out + (size_t)rowg*256;
    orow[tid]      = e0*inv;
    orow[tid+64]   = e1*inv;
    orow[tid+128]  = e2*inv;
    orow[tid+192]  = e3*inv;
  }
}

extern "C" void kernel_launch(void* const* d_in, const int* in_sizes, int n_in,
                              void* d_out, int out_size, void* d_ws, size_t ws_size,
                              hipStream_t stream) {
  (void)in_sizes; (void)n_in; (void)out_size;
  const float* x   = (const float*)d_in[0];
  const float* Wgx = (const float*)d_in[1];
  const float* Wgh = (const float*)d_in[2];
  const float* bg  = (const float*)d_in[3];
  const float* Wix = (const float*)d_in[4];
  const float* Wih = (const float*)d_in[5];
  const float* bi  = (const float*)d_in[6];
  const float* Wfx = (const float*)d_in[7];
  const float* Wfh = (const float*)d_in[8];
  const float* bf  = (const float*)d_in[9];
  const float* Wox = (const float*)d_in[10];
  const float* Woh = (const float*)d_in[11];
  const float* bo  = (const float*)d_in[12];
  const float* Wph = (const float*)d_in[13];
  const float* bp  = (const float*)d_in[14];

  char* ws = (char*)d_ws;
  f16*   WT   = (f16*)(ws + WS_WT);
  f16*   WphT = (f16*)(ws + WS_WPHT);
  f16*   hbuf = (f16*)(ws + WS_HBUF);
  float* lg   = (float*)(ws + WS_LG);
  u32*   cnt  = (u32*)(ws + WS_CNT);
  u32*   tick = (u32*)(ws + WS_TICK);
  const int use_xh = (ws_size >= (size_t)WS_XH_END) ? 1 : 0;
  f16*   xh   = (f16*)(ws + WS_XH);

  // h0 = 0 (buffer 0); flags + tickets = 0 (replay-safe)
  hipMemsetAsync(hbuf, 0, 524288, stream);
  hipMemsetAsync(cnt, 0, 2048 + 64, stream);

  prep_wt<<<5120, 256, 0, stream>>>(Wgh, Wih, Wfh, Woh, Wgx, Wix, Wfx, Wox, WT);
  prep_wph<<<256, 256, 0, stream>>>(Wph, WphT);
  if (use_xh)
    prep_x16<<<8192, 256, 0, stream>>>(x, xh);
  lstm_main<<<256, 512, 0, stream>>>(x, xh, use_xh, WT, WphT, hbuf,
                                     bg, bi, bf, bo, bp,
                                     lg, cnt, tick, (float*)d_out);
}

// Round 15
// 2471.692 us; speedup vs baseline: 1.8439x; 1.0531x over previous
//
#include <hip/hip_runtime.h>

// LSTM fused kernel for MI355X (gfx950) — round 15: r12 base (best: 2485us)
// + ONE change: x pre-converted to fp16 (xh) by a prep kernel, so x-staging
// is 1 uint4 load + 1 ds_write (was 2 float4 + 8 cvt + 2 writes).
// r14's ticket-release/zbuf-dbuf experiment REVERTED (cost ~120us: LDS-atomic
// serialization + wave drift > barrier cost at this slot size).
// 256 blocks x 512 threads (8 waves, 2/SIMD). Group = measured XCD; 32 batch
// rows split into tiles A/B (16 rows) alternated per slot.
// Transposed MFMA: wave (hgrp=wv&1, kh=wv>>1), z^T = W·[h|x]^T, lane holds
// all 4 gates of one (row,hcol); cross-kh reduce via single 32KB zbuf;
// c in regs; gates all-lanes. 3 syncthreads/slot (A: stage, B: zbuf, C: end).
// Sync: relaxed agent flags + per-wave buffer_inv sc0 acquire, early-poll,
// deferred inv; threadfence fallback; guards 1<<18.
// Workspace: WT fp16 [4096][1280] @0, WphT @10485760,
// hbuf [2][256][1024] @11010048, lg @12058624, cnt @12320768, tick @12322816,
// xh fp16 [256][512][256] @16777216 (only if ws_size >= 83886080).

typedef _Float16 f16;
typedef _Float16 f16x8 __attribute__((ext_vector_type(8)));
typedef _Float16 f16x4 __attribute__((ext_vector_type(4)));
typedef float f32x4 __attribute__((ext_vector_type(4)));
typedef unsigned int u32;

#define WS_WT    0
#define WS_WPHT  10485760
#define WS_HBUF  11010048
#define WS_LG    12058624
#define WS_CNT   12320768
#define WS_TICK  12322816
#define WS_XH    16777216
#define WS_XH_END 83886080

// LDS: A-tile[2] [16 rows][2560B] @0/@40960 (4-bit row swizzle);
// zbuf [kh4][512 x 16B] @81920 (32 KB, slot16 = (row*32+hcol) ^ (row&7));
// bcast @114688.
#define ZB    81920u
#define BCAST 114688

__device__ __forceinline__ float sigm(float v) { return 1.0f / (1.0f + __expf(-v)); }
__device__ __forceinline__ float tanhfast(float v) {
  float t = __expf(-2.0f * fabsf(v));
  float r = (1.0f - t) / (1.0f + t);
  return v < 0.0f ? -r : r;
}

// ---------- prep: WT[n][k], n=gate*1024+j (z-col), k<1024 -> Wh[k][j], else Wx[k-1024][j]
__global__ __launch_bounds__(256) void prep_wt(
    const float* __restrict__ Wgh, const float* __restrict__ Wih,
    const float* __restrict__ Wfh, const float* __restrict__ Woh,
    const float* __restrict__ Wgx, const float* __restrict__ Wix,
    const float* __restrict__ Wfx, const float* __restrict__ Wox,
    f16* __restrict__ WT)
{
  __shared__ float tile[32][33];
  int bid = blockIdx.x;
  int gate = bid / 1280;
  int rem  = bid % 1280;
  int jt = rem / 40, kt = rem % 40;
  const float* srcH = (gate==0)?Wgh:(gate==1)?Wih:(gate==2)?Wfh:Woh;
  const float* srcX = (gate==0)?Wgx:(gate==1)?Wix:(gate==2)?Wfx:Wox;
  const float* src = (kt < 32) ? (srcH + (size_t)(kt*32)*1024)
                               : (srcX + (size_t)(kt*32 - 1024)*1024);
  int t = threadIdx.x;
  {
    int jl = t & 31, kg = t >> 5;
#pragma unroll
    for (int it = 0; it < 4; ++it) {
      int kl = kg + it*8;
      tile[kl][jl] = src[(size_t)kl*1024 + jt*32 + jl];
    }
  }
  __syncthreads();
  {
    int kl = t & 31, jg = t >> 5;
#pragma unroll
    for (int it = 0; it < 4; ++it) {
      int jl2 = jg + it*8;
      WT[(size_t)(gate*1024 + jt*32 + jl2)*1280 + kt*32 + kl] = (f16)tile[kl][jl2];
    }
  }
}

// ---------- prep: WphT[oc][k] = W_ph[k][oc], fp16
__global__ __launch_bounds__(256) void prep_wph(const float* __restrict__ Wph,
                                                f16* __restrict__ WphT)
{
  __shared__ float tile[32][33];
  int bid = blockIdx.x;
  int jt = bid & 7, kt = bid >> 3;
  int t = threadIdx.x;
  {
    int jl = t & 31, kg = t >> 5;
#pragma unroll
    for (int it = 0; it < 4; ++it) {
      int kl = kg + it*8;
      tile[kl][jl] = Wph[(size_t)(kt*32 + kl)*256 + jt*32 + jl];
    }
  }
  __syncthreads();
  {
    int kl = t & 31, jg = t >> 5;
#pragma unroll
    for (int it = 0; it < 4; ++it) {
      int jl2 = jg + it*8;
      WphT[(size_t)(jt*32 + jl2)*1024 + kt*32 + kl] = (f16)tile[kl][jl2];
    }
  }
}

// ---------- prep: x f32 -> f16 (33.5M elems, 16/thread)
__global__ __launch_bounds__(256) void prep_x16(const float* __restrict__ x,
                                                f16* __restrict__ xh)
{
  size_t i = ((size_t)blockIdx.x*256 + threadIdx.x) * 16;
  const float4* src = (const float4*)(x + i);
  f16x4* dst = (f16x4*)(xh + i);
#pragma unroll
  for (int j = 0; j < 4; ++j) {
    float4 v = src[j];
    f16x4 h; h[0]=(f16)v.x; h[1]=(f16)v.y; h[2]=(f16)v.z; h[3]=(f16)v.w;
    dst[j] = h;
  }
}

// ---------- main persistent LSTM kernel
__global__ __launch_bounds__(512, 2) void lstm_main(
    const float* __restrict__ x, const f16* __restrict__ xh, int use_xh,
    const f16* __restrict__ WT, const f16* __restrict__ WphT,
    f16* __restrict__ hbuf,
    const float* __restrict__ bgp, const float* __restrict__ bip,
    const float* __restrict__ bfp, const float* __restrict__ bop,
    const float* __restrict__ bpp, float* __restrict__ lg,
    u32* __restrict__ cnt, u32* __restrict__ tick, float* __restrict__ out)
{
  __shared__ __align__(16) char smem[114704];
  const int tid  = threadIdx.x;
  const int lane = tid & 63;
  const int wv   = tid >> 6;
  const int hgrp = wv & 1;         // h-col half (16 cols)
  const int kh   = wv >> 1;        // K quarter (320)
  const int l15 = lane & 15, l4 = lane >> 4;

  // ---- measure XCD, take ticket on per-XCD counter
  u32 myxcd;
  asm volatile("s_getreg_b32 %0, hwreg(HW_REG_XCC_ID)" : "=s"(myxcd));
  myxcd &= 7u;
  if (tid == 0) {
    u32 t = __hip_atomic_fetch_add(tick + myxcd, 1u,
                                   __ATOMIC_RELAXED, __HIP_MEMORY_SCOPE_AGENT);
    *(volatile u32*)(smem + BCAST) = t;
  }
  if (wv == 0) {
    u32 v = 0;
    int guard = 0;
    for (;;) {
      v = (lane < 8) ? __hip_atomic_load(tick + lane, __ATOMIC_RELAXED,
                                         __HIP_MEMORY_SCOPE_AGENT) : 0u;
      u32 sum = v;
      sum += __shfl_xor(sum, 1);
      sum += __shfl_xor(sum, 2);
      sum += __shfl_xor(sum, 4);
      if (__shfl(sum, 0) == 256u) break;
      __builtin_amdgcn_s_sleep(1);
      if (++guard > (1 << 20)) break;
    }
    int even = __all((lane < 8) ? (v == 32u) : 1);
    if (lane == 0) *(volatile u32*)(smem + BCAST + 4) = (u32)even;
  }
  __syncthreads();
  const bool xloc = (*(volatile u32*)(smem + BCAST + 4)) != 0u;
  const u32 myticket = *(volatile u32*)(smem + BCAST);
  const int xg = xloc ? (int)myxcd    : (blockIdx.x & 7);   // batch-tile group
  const int cg = xloc ? (int)myticket : (blockIdx.x >> 3);  // column slice 0..31
  u32* flg = cnt + xg*64;           // [tileA flags 0..31][tileB flags 32..63]

  // ---- weight-stationary A-op fragments: [10 kk][4 frags] = 160 regs.
  // Lane l15 = m = hcolsub*4 + gate (gate-minor interleave).
  f16x8 Breg[10][4];
  {
    const int gate = l15 & 3, hsub = l15 >> 2;
#pragma unroll
    for (int f = 0; f < 4; ++f) {
      const int n = gate*1024 + cg*32 + hgrp*16 + f*4 + hsub;
      const f16* wb = WT + (size_t)n*1280 + kh*320 + l4*8;
#pragma unroll
      for (int kk = 0; kk < 10; ++kk) {
        Breg[kk][f] = *(const f16x8*)(wb + kk*32);
        asm volatile("" : "+v"(Breg[kk][f]));   // pin: no remat
      }
    }
  }

  // per-thread bias (gates phase handles hcol = tid&31)
  const int bcol = cg*32 + (tid & 31);
  const float bgr = bgp[bcol], bir = bip[bcol], bfr = bfp[bcol], bor = bop[bcol];

  // B-op (activations) frag addressing: lane l15 = batch row
  const u32 aoff = (u32)l15*2560u + (u32)(kh*640 + l4*16);
  const u32 aswz = (u32)l15 << 4;
  // cooperative staging: 16 rows x 32 segs (512 threads), 4-bit swizzle
  const int srow = tid >> 5;
  const int sseg = tid & 31;
  const u32 swzr = (u32)srow << 4;

  // c state in registers (gates thread owns (row=tid>>5, hcol=tid&31))
  float cA = 0.0f, cB = 0.0f;

  u32 pre = 0xFFFFFFFFu;
  bool preOK = false;

#pragma unroll 1
  for (int slot = 0; slot < 1024; ++slot) {
    const int T = slot & 1, s = slot >> 1;
    const u32 Abase = (u32)T * 40960u;
    u32* flgT = flg + T*32;
    const int grow = xg*32 + T*16 + srow;

    // ---- x stage (tile-T x region dead since slot-2) — overlaps flag latency
    if (use_xh) {
      const char* xrow = (const char*)xh + ((size_t)grow*512 + (size_t)s)*512;
      uint4 v = *(const uint4*)(xrow + sseg*16);
      *(uint4*)(smem + Abase + (((u32)srow*2560u + 2048u + (u32)sseg*16u) ^ swzr)) = v;
    } else {
      const float* xsrc = x + ((size_t)grow*512 + (size_t)s)*256;
      float4 xv0 = *(const float4*)(xsrc + (sseg     )*4);
      float4 xv1 = *(const float4*)(xsrc + (sseg + 32)*4);
      f16x4 hv;
      hv[0] = (f16)xv0.x; hv[1] = (f16)xv0.y; hv[2] = (f16)xv0.z; hv[3] = (f16)xv0.w;
      *(f16x4*)(smem + Abase + (((u32)srow*2560u + 2048u + 8u*(u32)(sseg     )) ^ swzr)) = hv;
      hv[0] = (f16)xv1.x; hv[1] = (f16)xv1.y; hv[2] = (f16)xv1.z; hv[3] = (f16)xv1.w;
      *(f16x4*)(smem + Abase + (((u32)srow*2560u + 2048u + 8u*(u32)(sseg + 32)) ^ swzr)) = hv;
    }
    // ---- per-wave barrier: only if this wave's early-poll didn't confirm
    if (s > 0 && !preOK) {
      const u32 tgt = (u32)s;
      u32 v = tgt;
      int guard = 0;
      for (;;) {
        if (lane < 32)
          v = __hip_atomic_load(flgT + lane, __ATOMIC_RELAXED,
                                __HIP_MEMORY_SCOPE_AGENT);
        if (__all(v >= tgt)) break;
        __builtin_amdgcn_s_sleep(1);
        if (++guard > (1 << 18)) break;
      }
      if (lane == 0) {
        if (xloc) { asm volatile("buffer_inv sc0\n\ts_waitcnt vmcnt(0)" ::: "memory"); }
        else      { __threadfence(); }
      }
    }
    // ---- cooperative h stage [16 rows x 1024] fp16, XOR-swizzled
    {
      const f16* hsrc = hbuf + (size_t)(s & 1)*262144 + (size_t)grow*1024;
#pragma unroll
      for (int j = 0; j < 4; ++j) {
        int chunk = sseg + 32*j;
        uint4 v = *(const uint4*)(hsrc + chunk*8);
        *(uint4*)(smem + Abase + (((u32)srow*2560u + 16u*(u32)chunk) ^ swzr)) = v;
      }
    }
    __syncthreads();   // (A) staging complete
    // ---- K loop: K/4 per wave; one av feeds 4 col-frags (gates in lanes)
    f32x4 acc0 = {}, acc1 = {}, acc2 = {}, acc3 = {};
#pragma unroll
    for (int kk = 0; kk < 10; ++kk) {
      f16x8 av = *(const f16x8*)(smem + Abase + ((aoff + (u32)kk*64u) ^ aswz));
      acc0 = __builtin_amdgcn_mfma_f32_16x16x32_f16(Breg[kk][0], av, acc0, 0, 0, 0);
      acc1 = __builtin_amdgcn_mfma_f32_16x16x32_f16(Breg[kk][1], av, acc1, 0, 0, 0);
      acc2 = __builtin_amdgcn_mfma_f32_16x16x32_f16(Breg[kk][2], av, acc2, 0, 0, 0);
      acc3 = __builtin_amdgcn_mfma_f32_16x16x32_f16(Breg[kk][3], av, acc3, 0, 0, 0);
    }
    // ---- early poll (ALL waves): next slot's flags, consumed after gates
    {
      const int nT = (slot + 1) & 1, nS = (slot + 1) >> 1;
      pre = 0xFFFFFFFFu;
      if (nS > 0 && nS < 512 && lane < 32)
        pre = __hip_atomic_load(flg + nT*32 + lane, __ATOMIC_RELAXED,
                                __HIP_MEMORY_SCOPE_AGENT);
    }
    // ---- zbuf partial write: f32x4 (4 gates) at slot16=(row*32+hcol)^(row&7)
    {
      const u32 zkh = ZB + (u32)kh*8192u;
#pragma unroll
      for (int f = 0; f < 4; ++f) {
        const u32 hcol = (u32)(hgrp*16 + f*4 + l4);
        const u32 s16 = ((u32)(l15*32) + hcol) ^ ((u32)(l15 & 7));
        f32x4 acc = (f==0)?acc0:(f==1)?acc1:(f==2)?acc2:acc3;
        *(f32x4*)(smem + zkh + s16*16u) = acc;
      }
    }
    __syncthreads();   // (B) zbuf ready
    // ---- gates: thread (row=tid>>5, hcol=tid&31), all lanes active
    {
      f16* hw = hbuf + (size_t)((s & 1) ^ 1)*262144;
      const int row = tid >> 5, hcol = tid & 31;
      const u32 s16 = ((u32)(row*32) + (u32)hcol) ^ ((u32)(row & 7));
      const u32 ro = s16*16u;
      f32x4 z0 = *(const f32x4*)(smem + ZB +        ro);
      f32x4 z1 = *(const f32x4*)(smem + ZB + 8192u  + ro);
      f32x4 z2 = *(const f32x4*)(smem + ZB + 16384u + ro);
      f32x4 z3 = *(const f32x4*)(smem + ZB + 24576u + ro);
      float zg = z0[0] + z1[0] + z2[0] + z3[0] + bgr;
      float zi = z0[1] + z1[1] + z2[1] + z3[1] + bir;
      float zf = z0[2] + z1[2] + z2[2] + z3[2] + bfr;
      float zo = z0[3] + z1[3] + z2[3] + z3[3] + bor;
      float cv = T ? cB : cA;
      float gv = tanhfast(zg);
      float iv = sigm(zi);
      float fv = sigm(zf);
      float ov = sigm(zo);
      float cn = gv*iv + cv*fv;
      if (T) cB = cn; else cA = cn;
      hw[(size_t)(xg*32 + T*16 + row)*1024 + cg*32 + hcol] = (f16)(tanhfast(cn) * ov);
    }
    // ---- preOK eval + deferred inv (per wave)
    {
      const int nS = (slot + 1) >> 1;
      bool ok = (nS >= 512) || __all(pre >= (u32)nS);
      preOK = xloc && ok;
      if (preOK && nS < 512 && lane == 0) {
        asm volatile("buffer_inv sc0\n\ts_waitcnt vmcnt(0)" ::: "memory");
      }
    }
    __syncthreads();   // (C) drains h stores + orders inv before next slot
    if (tid == 0) {
      if (!xloc) __threadfence();
      __hip_atomic_store(flgT + cg, (u32)(s + 1),
                         __ATOMIC_RELAXED, __HIP_MEMORY_SCOPE_AGENT);
    }
  }

  // ---- epilogue: wait both tiles at 512, logits = h @ WphT + bp
  if (wv == 0) {
    u32 v = 512u;
    int guard = 0;
    for (;;) {
      v = __hip_atomic_load(flg + lane, __ATOMIC_RELAXED,
                            __HIP_MEMORY_SCOPE_AGENT);   // lanes 0-63 = A,B
      if (__all(v >= 512u)) break;
      __builtin_amdgcn_s_sleep(1);
      if (++guard > (1 << 18)) break;
    }
    if (lane == 0) {
      if (xloc) { asm volatile("buffer_inv sc0\n\ts_waitcnt vmcnt(0)" ::: "memory"); }
      else      { __threadfence(); }
    }
  }
  __syncthreads();
  {
#pragma unroll 1
    for (int p = 0; p < 32; ++p) {
      int rowl = wv*4 + (p >> 3);
      int oc   = p & 7;
      const f16* hp = hbuf + (size_t)(xg*32 + rowl)*1024 + lane*16;  // buf 0 = h_T
      const f16* wp = WphT + (size_t)(cg*8 + oc)*1024 + lane*16;
      f16x8 h0 = *(const f16x8*)hp;
      f16x8 h1 = *(const f16x8*)(hp + 8);
      f16x8 w0 = *(const f16x8*)wp;
      f16x8 w1 = *(const f16x8*)(wp + 8);
      float sum = 0.f;
#pragma unroll
      for (int q = 0; q < 8; ++q)
        sum += (float)h0[q]*(float)w0[q] + (float)h1[q]*(float)w1[q];
#pragma unroll
      for (int d = 1; d < 64; d <<= 1) sum += __shfl_xor(sum, d);
      if (lane == 0)
        lg[(size_t)(xg*32 + rowl)*256 + cg*8 + oc] = sum + bpp[cg*8 + oc];
    }
  }
  __syncthreads();   // drain lg stores
  if (tid == 0) {
    if (!xloc) __threadfence();
    __hip_atomic_store(flg + cg, 513u, __ATOMIC_RELAXED, __HIP_MEMORY_SCOPE_AGENT);
  }
  if (wv == 0) {
    u32 v = 513u;
    int guard = 0;
    for (;;) {
      if (lane < 32)
        v = __hip_atomic_load(flg + lane, __ATOMIC_RELAXED, __HIP_MEMORY_SCOPE_AGENT);
      if (__all(v >= 513u)) break;
      __builtin_amdgcn_s_sleep(1);
      if (++guard > (1 << 18)) break;
    }
    if (lane == 0) {
      if (xloc) { asm volatile("buffer_inv sc0\n\ts_waitcnt vmcnt(0)" ::: "memory"); }
      else      { __threadfence(); }
    }
  }
  __syncthreads();
  // ---- softmax: this block handles row xg*32+cg, wave 0 only
  if (tid < 64) {
    int rowg = xg*32 + cg;
    const float* lr = lg + (size_t)rowg*256;
    float v0 = lr[tid], v1 = lr[tid+64], v2 = lr[tid+128], v3 = lr[tid+192];
    float mx = fmaxf(fmaxf(v0, v1), fmaxf(v2, v3));
#pragma unroll
    for (int d = 1; d < 64; d <<= 1) mx = fmaxf(mx, __shfl_xor(mx, d));
    float e0 = __expf(v0-mx), e1 = __expf(v1-mx), e2 = __expf(v2-mx), e3 = __expf(v3-mx);
    float sm = e0+e1+e2+e3;
#pragma unroll
    for (int d = 1; d < 64; d <<= 1) sm += __shfl_xor(sm, d);
    float inv = 1.0f / sm;
    float* orow = out + (size_t)rowg*256;
    orow[tid]      = e0*inv;
    orow[tid+64]   = e1*inv;
    orow[tid+128]  = e2*inv;
    orow[tid+192]  = e3*inv;
  }
}

extern "C" void kernel_launch(void* const* d_in, const int* in_sizes, int n_in,
                              void* d_out, int out_size, void* d_ws, size_t ws_size,
                              hipStream_t stream) {
  (void)in_sizes; (void)n_in; (void)out_size;
  const float* x   = (const float*)d_in[0];
  const float* Wgx = (const float*)d_in[1];
  const float* Wgh = (const float*)d_in[2];
  const float* bg  = (const float*)d_in[3];
  const float* Wix = (const float*)d_in[4];
  const float* Wih = (const float*)d_in[5];
  const float* bi  = (const float*)d_in[6];
  const float* Wfx = (const float*)d_in[7];
  const float* Wfh = (const float*)d_in[8];
  const float* bf  = (const float*)d_in[9];
  const float* Wox = (const float*)d_in[10];
  const float* Woh = (const float*)d_in[11];
  const float* bo  = (const float*)d_in[12];
  const float* Wph = (const float*)d_in[13];
  const float* bp  = (const float*)d_in[14];

  char* ws = (char*)d_ws;
  f16*   WT   = (f16*)(ws + WS_WT);
  f16*   WphT = (f16*)(ws + WS_WPHT);
  f16*   hbuf = (f16*)(ws + WS_HBUF);
  float* lg   = (float*)(ws + WS_LG);
  u32*   cnt  = (u32*)(ws + WS_CNT);
  u32*   tick = (u32*)(ws + WS_TICK);
  const int use_xh = (ws_size >= (size_t)WS_XH_END) ? 1 : 0;
  f16*   xh   = (f16*)(ws + WS_XH);

  // h0 = 0 (buffer 0); flags + tickets = 0 (replay-safe)
  hipMemsetAsync(hbuf, 0, 524288, stream);
  hipMemsetAsync(cnt, 0, 2048 + 64, stream);

  prep_wt<<<5120, 256, 0, stream>>>(Wgh, Wih, Wfh, Woh, Wgx, Wix, Wfx, Wox, WT);
  prep_wph<<<256, 256, 0, stream>>>(Wph, WphT);
  if (use_xh)
    prep_x16<<<8192, 256, 0, stream>>>(x, xh);
  lstm_main<<<256, 512, 0, stream>>>(x, xh, use_xh, WT, WphT, hbuf,
                                     bg, bi, bf, bo, bp,
                                     lg, cnt, tick, (float*)d_out);
}